// Round 9
// baseline (397.630 us; speedup 1.0000x reference)
//
#include <hip/hip_runtime.h>
#include <math.h>

#define N_NODES 50000
#define N_EDGES 800000
#define D_IN 64
#define D_HID 128
#define SCAN_B 256
#define N_SB ((N_NODES + SCAN_B - 1) / SCAN_B)  // 196
#define NPB 256                                  // nodes per bucket
#define NB ((N_NODES + NPB - 1) / NPB)           // 196 buckets
#define P1_BLOCKS 256
#define EPB (N_EDGES / P1_BLOCKS)                // 3125 edges per pass-1 block
#define XCVT_B (N_NODES * D_IN / 4 / 256)        // 3125 blocks for xcvt part

typedef unsigned short u16;
typedef unsigned int u32;
typedef __attribute__((ext_vector_type(8))) short short8;
typedef __attribute__((ext_vector_type(4))) float f32x4;

union U4S8 { uint4 u; short8 s; };

__device__ __forceinline__ float bf2f(u16 u) {
    u32 x = ((u32)u) << 16;
    float f; __builtin_memcpy(&f, &x, 4); return f;
}
__device__ __forceinline__ float bflo(u32 w) {  // low bf16 of packed u32
    u32 x = w << 16;
    float f; __builtin_memcpy(&f, &x, 4); return f;
}
__device__ __forceinline__ float bfhi(u32 w) {  // high bf16 of packed u32
    u32 x = w & 0xFFFF0000u;
    float f; __builtin_memcpy(&f, &x, 4); return f;
}
__device__ __forceinline__ u16 f2bf(float f) {  // round-to-nearest-even
    u32 x; __builtin_memcpy(&x, &f, 4);
    x += 0x7fffu + ((x >> 16) & 1u);
    return (u16)(x >> 16);
}
__device__ __forceinline__ u32 pk2(float a, float b) {  // pack 2 bf16 into u32
    return (u32)f2bf(a) | ((u32)f2bf(b) << 16);
}
// relu on 2 packed bf16 (zero halves with sign bit set) — branchless
__device__ __forceinline__ u32 relu2(u32 w) {
    u32 b = (w >> 15) & 0x00010001u;
    u32 m01 = b ^ 0x00010001u;        // 1 per half to KEEP
    u32 M = (m01 << 16) - m01;        // 0xFFFF per kept half
    return w & M;
}

// ============================ CSR build ============================

// count + (block 0) zero bn[1024] and esrc tail padding
__global__ void count_kernel(const int* __restrict__ dst, int* __restrict__ deg,
                             float* __restrict__ bn, int* __restrict__ esrc) {
    int i = blockIdx.x * blockDim.x + threadIdx.x;
    if (i < N_EDGES) atomicAdd(&deg[dst[i]], 1);
    if (blockIdx.x == 0) {
        int t = threadIdx.x;
        ((float4*)bn)[t] = make_float4(0.f, 0.f, 0.f, 0.f);  // 256*4 = 1024
        if (t < 16) esrc[N_EDGES + t] = 0;
    }
}

__global__ __launch_bounds__(SCAN_B) void scan_reduce_kernel(const int* __restrict__ deg,
                                                             int* __restrict__ bsum) {
    __shared__ int s[SCAN_B];
    int i = blockIdx.x * SCAN_B + threadIdx.x;
    int v = (i < N_NODES) ? deg[i] : 0;
    s[threadIdx.x] = v;
    __syncthreads();
    #pragma unroll
    for (int o = SCAN_B / 2; o > 0; o >>= 1) {
        if (threadIdx.x < o) s[threadIdx.x] += s[threadIdx.x + o];
        __syncthreads();
    }
    if (threadIdx.x == 0) bsum[blockIdx.x] = s[0];
}

__global__ __launch_bounds__(SCAN_B) void scan_sums_kernel(const int* __restrict__ bsum,
                                                           int* __restrict__ boff) {
    __shared__ int s[SCAN_B];
    int t = threadIdx.x;
    int v = (t < N_SB) ? bsum[t] : 0;
    s[t] = v;
    __syncthreads();
    #pragma unroll
    for (int o = 1; o < SCAN_B; o <<= 1) {
        int u = (t >= o) ? s[t - o] : 0;
        __syncthreads();
        s[t] += u;
        __syncthreads();
    }
    if (t < N_SB) boff[t] = s[t] - v;  // exclusive
}

// writes off[] AND (t==0) bucket cursors gcur[b] = boff[b]  (NPB == SCAN_B)
__global__ __launch_bounds__(SCAN_B) void scan_write_kernel(const int* __restrict__ deg,
                                                            const int* __restrict__ boff,
                                                            int* __restrict__ off,
                                                            int* __restrict__ gcur) {
    __shared__ int s[SCAN_B];
    int t = threadIdx.x;
    int i = blockIdx.x * SCAN_B + t;
    int v = (i < N_NODES) ? deg[i] : 0;
    s[t] = v;
    __syncthreads();
    #pragma unroll
    for (int o = 1; o < SCAN_B; o <<= 1) {
        int u = (t >= o) ? s[t - o] : 0;
        __syncthreads();
        s[t] += u;
        __syncthreads();
    }
    int incl = s[t] + boff[blockIdx.x];
    if (i < N_NODES) off[i] = incl - v;
    if (i == N_NODES - 1) off[N_NODES] = incl;
    if (t == 0) gcur[blockIdx.x] = boff[blockIdx.x];
}

// ==================== binned scatter pass 1 (packed u32 ebuf) ====================
__global__ __launch_bounds__(256) void bin_pass1_kernel(const int* __restrict__ src,
                                                        const int* __restrict__ dst,
                                                        int* __restrict__ gcur,
                                                        u32* __restrict__ ebuf) {
    __shared__ int hist[NB];
    __shared__ int base[NB];
    const int tid = threadIdx.x;
    const int e0 = blockIdx.x * EPB, e1 = e0 + EPB;
    for (int b = tid; b < NB; b += 256) hist[b] = 0;
    __syncthreads();
    for (int i = e0 + tid; i < e1; i += 256)
        atomicAdd(&hist[dst[i] >> 8], 1);
    __syncthreads();
    for (int b = tid; b < NB; b += 256) {
        base[b] = atomicAdd(&gcur[b], hist[b]);
        hist[b] = 0;  // reuse as block-local cursor
    }
    __syncthreads();
    for (int i = e0 + tid; i < e1; i += 256) {
        int d = dst[i];
        int b = d >> 8;
        int slot = base[b] + atomicAdd(&hist[b], 1);
        ebuf[slot] = ((u32)src[i] << 16) | (u32)d;
    }
}

// ============ pass 2 (bucket->node scatter) + xcvt + wprep, one launch ========
// blocks [0, NB): pass2; [NB, NB+XCVT_B): x->bf16; [NB+XCVT_B, +8): W frags.
__global__ __launch_bounds__(256) void p2xw_kernel(const int* __restrict__ off,
                                                   const u32* __restrict__ ebuf,
                                                   int* __restrict__ esrc,
                                                   const float* __restrict__ x,
                                                   u16* __restrict__ xb,
                                                   u16* __restrict__ rb,
                                                   const float* __restrict__ W1,
                                                   const float* __restrict__ W2,
                                                   u16* __restrict__ w1f,
                                                   u16* __restrict__ w2f) {
    const int tid = threadIdx.x;
    if (blockIdx.x < NB) {
        __shared__ int soff[NPB];
        __shared__ int cur[NPB];
        const int b = blockIdx.x;
        const int n0 = b * NPB;
        soff[tid] = off[min(n0 + tid, N_NODES)];
        cur[tid] = 0;
        __syncthreads();
        const int e0 = soff[0];
        const int e1 = off[min(n0 + NPB, N_NODES)];
        for (int i = e0 + tid; i < e1; i += 256) {
            u32 p = ebuf[i];
            int dl = (int)(p & 0xFFFFu) - n0;
            int slot = soff[dl] + atomicAdd(&cur[dl], 1);
            esrc[slot] = (int)(p >> 16);
        }
        return;
    }
    if (blockIdx.x < NB + XCVT_B) {
        int i = (blockIdx.x - NB) * 256 + tid;  // one float4 per thread
        float4 v = ((const float4*)x)[i];
        u32 lo = pk2(v.x, v.y), hi = pk2(v.z, v.w);
        ((uint2*)xb)[i] = make_uint2(lo, hi);
        ((uint2*)rb)[i] = make_uint2(relu2(lo), relu2(hi));
        return;
    }
    const int b = blockIdx.x - NB - XCVT_B;  // 0..7: layer*2 + (0=W1, 1=W2)
    const int L = b >> 1;
    if ((b & 1) == 0) {
        const float* W = W1 + (size_t)L * 64 * 128;
        u16* outp = w1f + (size_t)L * 8192;
        for (int idx = tid; idx < 1024; idx += 256) {
            int ln = idx & 63, th = idx >> 6;          // th = t*2+half
            int half = th & 1, t = th >> 1;
            int k0 = half * 32 + (ln >> 4) * 8;
            int n = t * 16 + (ln & 15);
            uint4 o;
            o.x = pk2(W[(k0 + 0) * 128 + n], W[(k0 + 1) * 128 + n]);
            o.y = pk2(W[(k0 + 2) * 128 + n], W[(k0 + 3) * 128 + n]);
            o.z = pk2(W[(k0 + 4) * 128 + n], W[(k0 + 5) * 128 + n]);
            o.w = pk2(W[(k0 + 6) * 128 + n], W[(k0 + 7) * 128 + n]);
            *(uint4*)&outp[(size_t)idx * 8] = o;
        }
    } else {
        const float* W = W2 + (size_t)L * 128 * 64;
        u16* outp = w2f + (size_t)L * 8192;
        for (int idx = tid; idx < 1024; idx += 256) {
            int ln = idx & 63, th = idx >> 6;          // th = t*4+ks
            int ks = th & 3, t = th >> 2;
            int k0 = ks * 32 + (ln >> 4) * 8;
            int n = t * 16 + (ln & 15);
            uint4 o;
            o.x = pk2(W[(k0 + 0) * 64 + n], W[(k0 + 1) * 64 + n]);
            o.y = pk2(W[(k0 + 2) * 64 + n], W[(k0 + 3) * 64 + n]);
            o.z = pk2(W[(k0 + 4) * 64 + n], W[(k0 + 5) * 64 + n]);
            o.w = pk2(W[(k0 + 6) * 64 + n], W[(k0 + 7) * 64 + n]);
            *(uint4*)&outp[(size_t)idx * 8] = o;
        }
    }
}

// ==================== softmax aggregation + residual (bf16 in/out) ============
// lane = (edge-slot, channel-pair): lane ln covers channels {2cp, 2cp+1}
// (cp = ln&31) of edge slot sl = ln>>5. One u32 load covers 2 channels; one
// wave-level load instruction covers 2 edges' 128B rows (256 B). Per 16 edges:
// 8 vmem instructions (vs 16 at lane=channel), same bytes in flight.
// esrc indices wave-uniform -> SGPR loads. Tail = one branchless masked iter.
__global__ __launch_bounds__(256) void agg_kernel(const u16* __restrict__ xb,
                                                  const u16* __restrict__ rb,
                                                  const int* __restrict__ off,
                                                  const int* __restrict__ esrc,
                                                  u16* __restrict__ h) {
    const int node = blockIdx.x * 4 + (threadIdx.x >> 6);
    const int ln = threadIdx.x & 63;
    const int cp = ln & 31;              // channel pair: channels 2cp, 2cp+1
    const int sl = ln >> 5;              // edge slot 0/1
    const int jb = __builtin_amdgcn_readfirstlane(off[node]);
    const int je = __builtin_amdgcn_readfirstlane(off[node + 1]);
    // residual (hoisted): u32 of own row's channel pair
    const u32 xw = *(const u32*)&xb[(size_t)node * 64 + cp * 2];
    float s0 = 0.f, s1 = 0.f, t0 = 0.f, t1 = 0.f;
    int j = jb;
    const int nfull = (je - jb) >> 4;
    for (int it = 0; it < nfull; ++it, j += 16) {
        u32 w[8];
        #pragma unroll
        for (int kk = 0; kk < 8; kk++) {
            int idx = esrc[j + 2 * kk + sl];            // SGPR base, uniform pair
            w[kk] = *(const u32*)&rb[(size_t)idx * 64 + cp * 2];
        }
        #pragma unroll
        for (int kk = 0; kk < 8; kk++) {
            float m0 = bflo(w[kk]);                      // channel 2cp  (>= 0)
            float m1 = bfhi(w[kk]);                      // channel 2cp+1
            float p0 = __expf(m0);
            float p1 = __expf(m1);
            s0 += p0; t0 = fmaf(m0, p0, t0);
            s1 += p1; t1 = fmaf(m1, p1, t1);
        }
    }
    const int rem = je - j;               // 0..15
    if (rem > 0) {                        // one branchless masked iteration
        u32 w[8];
        #pragma unroll
        for (int kk = 0; kk < 8; kk++) {
            int idx = esrc[j + 2 * kk + sl];            // padding zeroed -> safe
            w[kk] = *(const u32*)&rb[(size_t)idx * 64 + cp * 2];
        }
        #pragma unroll
        for (int kk = 0; kk < 8; kk++) {
            bool act = (2 * kk + sl) < rem;
            float m0 = bflo(w[kk]);
            float m1 = bfhi(w[kk]);
            float p0 = act ? __expf(m0) : 0.f;
            float p1 = act ? __expf(m1) : 0.f;
            s0 += p0; t0 = fmaf(m0, p0, t0);
            s1 += p1; t1 = fmaf(m1, p1, t1);
        }
    }
    // combine the two edge slots
    s0 += __shfl_xor(s0, 32); t0 += __shfl_xor(t0, 32);
    s1 += __shfl_xor(s1, 32); t1 += __shfl_xor(t1, 32);
    if (sl == 0) {  // lanes 0..31 hold all 64 channels (2 each)
        // eps-cancellation: exp(r+eps)=e^eps*exp(r) cancels in t/s; add eps once.
        float v0 = t0 / (s0 + 1e-16f) + 1e-7f + bflo(xw);
        float v1 = t1 / (s1 + 1e-16f) + 1e-7f + bfhi(xw);
        *(u32*)&h[(size_t)node * 64 + cp * 2] = pk2(v0, v1);
    }
}

// ==================== GEMM1 (MFMA) + LDS-transpose epilogue + BN stats ========
#define SC1 136  // u16 stride: 272 B = 17*16B (aligned for uint4 readback)
__global__ __launch_bounds__(256) void gemm1_kernel(const u16* __restrict__ A,
                                                    const u16* __restrict__ Wf,
                                                    const float* __restrict__ bias,
                                                    u16* __restrict__ Bout,
                                                    float* __restrict__ S,
                                                    float* __restrict__ Q) {
    __shared__ u16 sC[64 * SC1];          // 17.4 KB
    __shared__ float sRed[2][4][128];     // 4 KB: [S/Q][wave][channel]
    const int tid = threadIdx.x;
    const int wave = tid >> 6, ln = tid & 63;
    const int lm = ln & 15, quad = ln >> 4;
    const int row0g = blockIdx.x * 64;
    const int row0 = row0g + wave * 16;
    const int rA = min(row0 + lm, N_NODES - 1);

    // A-frags: A[m=lm][k=quad*8+j], two K=32 halves
    U4S8 a0, a1;
    a0.u = *(const uint4*)&A[(size_t)rA * 64 + quad * 8];
    a1.u = *(const uint4*)&A[(size_t)rA * 64 + 32 + quad * 8];

    f32x4 acc[8];
    #pragma unroll
    for (int t = 0; t < 8; t++) {
        float b = bias[t * 16 + lm];
        acc[t] = (f32x4){b, b, b, b};
    }
    #pragma unroll
    for (int t = 0; t < 8; t++) {
        U4S8 b0, b1;
        b0.u = *(const uint4*)&Wf[(size_t)((t * 2 + 0) * 64 + ln) * 8];
        b1.u = *(const uint4*)&Wf[(size_t)((t * 2 + 1) * 64 + ln) * 8];
        acc[t] = __builtin_amdgcn_mfma_f32_16x16x32_bf16(a0.s, b0.s, acc[t], 0, 0, 0);
        acc[t] = __builtin_amdgcn_mfma_f32_16x16x32_bf16(a1.s, b1.s, acc[t], 0, 0, 0);
    }
    // BN partial stats from registers (C layout: row = quad*4+rg, col = t*16+lm)
    const int rbase = row0 + quad * 4;
    #pragma unroll
    for (int t = 0; t < 8; t++) {
        float ss = 0.f, qq = 0.f;
        #pragma unroll
        for (int rg = 0; rg < 4; rg++) {
            if (rbase + rg < N_NODES) {
                float v = acc[t][rg];
                ss += v; qq = fmaf(v, v, qq);
            }
        }
        ss += __shfl_xor(ss, 16); ss += __shfl_xor(ss, 32);
        qq += __shfl_xor(qq, 16); qq += __shfl_xor(qq, 32);
        if (quad == 0) {
            sRed[0][wave][t * 16 + lm] = ss;
            sRed[1][wave][t * 16 + lm] = qq;
        }
    }
    // transpose through LDS (C-layout -> row-major bf16 tile)
    const int lr0 = wave * 16 + quad * 4;
    #pragma unroll
    for (int t = 0; t < 8; t++) {
        #pragma unroll
        for (int rg = 0; rg < 4; rg++)
            sC[(lr0 + rg) * SC1 + t * 16 + lm] = f2bf(acc[t][rg]);
    }
    __syncthreads();
    // coalesced vectorized store
    const int c8 = (tid & 15) * 8;
    #pragma unroll
    for (int i = 0; i < 4; i++) {
        int lr = (tid >> 4) + i * 16;
        int r = row0g + lr;
        if (r < N_NODES)
            *(uint4*)&Bout[(size_t)r * 128 + c8] = *(const uint4*)&sC[lr * SC1 + c8];
    }
    // one atomic per column per block (cross-wave sums from sRed)
    if (tid < 128) {
        float v = sRed[0][0][tid] + sRed[0][1][tid] + sRed[0][2][tid] + sRed[0][3][tid];
        atomicAdd(&S[tid], v);
    } else {
        int c = tid - 128;
        float v = sRed[1][0][c] + sRed[1][1][c] + sRed[1][2][c] + sRed[1][3][c];
        atomicAdd(&Q[c], v);
    }
}

// ==================== GEMM2 (MFMA) + fused BN finalize + LDS epilogue =========
__device__ __forceinline__ float mish_f(float v) {
    if (v > 30.f) return v;
    float u = __expf(v);
    float t = (u + 1.f) * (u + 1.f);
    return v * (t - 1.f) / (t + 1.f);  // = v * tanh(softplus(v))
}

#define SC2B 72  // u16 stride for bf16 tile: 144 B = 9*16B
#define SC2F 68  // f32 stride for fp32 tile: 272 B = 17*16B
__global__ __launch_bounds__(256) void gemm2_kernel(const u16* __restrict__ H,
                                                    const float* __restrict__ S,
                                                    const float* __restrict__ Q,
                                                    const float* __restrict__ gamma,
                                                    const float* __restrict__ beta,
                                                    const u16* __restrict__ Wf,
                                                    const float* __restrict__ bias,
                                                    float* __restrict__ outf,
                                                    u16* __restrict__ xb,
                                                    u16* __restrict__ rb,
                                                    int dobf16) {
    __shared__ float sss[256];
    __shared__ __align__(16) char sCraw[64 * SC2F * 4];  // 17.4 KB
    u16* sCb = (u16*)sCraw;
    float* sCf = (float*)sCraw;
    const int tid = threadIdx.x;
    // fused BN finalize: per-channel scale/shift from global S/Q
    if (tid < 128) {
        float mean = S[tid] * (1.f / N_NODES);
        float var = fmaxf(Q[tid] * (1.f / N_NODES) - mean * mean, 0.f);
        float sc = gamma[tid] * rsqrtf(var + 1e-5f);
        sss[tid] = sc;
        sss[128 + tid] = beta[tid] - mean * sc;
    }
    __syncthreads();
    const int wave = tid >> 6, ln = tid & 63;
    const int lm = ln & 15, quad = ln >> 4;
    const int row0g = blockIdx.x * 64;
    const int row0 = row0g + wave * 16;
    const int rA = min(row0 + lm, N_NODES - 1);

    f32x4 acc[4];
    #pragma unroll
    for (int t = 0; t < 4; t++) {
        float b = bias[t * 16 + lm];
        acc[t] = (f32x4){b, b, b, b};
    }
    #pragma unroll
    for (int ks = 0; ks < 4; ks++) {
        const int k0 = ks * 32 + quad * 8;
        U4S8 h8;
        h8.u = *(const uint4*)&H[(size_t)rA * 128 + k0];
        U4S8 a;
        #pragma unroll
        for (int j2 = 0; j2 < 4; j2++) {
            int k = k0 + 2 * j2;
            float v0 = fmaxf(fmaf(bf2f((u16)h8.s[2 * j2]),     sss[k],     sss[128 + k]),     0.f);
            float v1 = fmaxf(fmaf(bf2f((u16)h8.s[2 * j2 + 1]), sss[k + 1], sss[128 + k + 1]), 0.f);
            ((u32*)&a.u)[j2] = pk2(v0, v1);
        }
        #pragma unroll
        for (int t = 0; t < 4; t++) {
            U4S8 b;
            b.u = *(const uint4*)&Wf[(size_t)((t * 4 + ks) * 64 + ln) * 8];
            acc[t] = __builtin_amdgcn_mfma_f32_16x16x32_bf16(a.s, b.s, acc[t], 0, 0, 0);
        }
    }
    const int lr0 = wave * 16 + quad * 4;
    if (dobf16) {
        #pragma unroll
        for (int t = 0; t < 4; t++) {
            #pragma unroll
            for (int rg = 0; rg < 4; rg++)
                sCb[(lr0 + rg) * SC2B + t * 16 + lm] = f2bf(mish_f(acc[t][rg]));
        }
        __syncthreads();
        const int c8 = (tid & 7) * 8;
        #pragma unroll
        for (int i = 0; i < 2; i++) {
            int lr = (tid >> 3) + i * 32;
            int r = row0g + lr;
            if (r < N_NODES) {
                uint4 val = *(const uint4*)&sCb[lr * SC2B + c8];
                *(uint4*)&xb[(size_t)r * 64 + c8] = val;
                uint4 rv;
                rv.x = relu2(val.x); rv.y = relu2(val.y);
                rv.z = relu2(val.z); rv.w = relu2(val.w);
                *(uint4*)&rb[(size_t)r * 64 + c8] = rv;
            }
        }
    } else {
        #pragma unroll
        for (int t = 0; t < 4; t++) {
            #pragma unroll
            for (int rg = 0; rg < 4; rg++)
                sCf[(lr0 + rg) * SC2F + t * 16 + lm] = acc[t][rg];
        }
        __syncthreads();
        const int c8 = (tid & 7) * 8;
        #pragma unroll
        for (int i = 0; i < 2; i++) {
            int lr = (tid >> 3) + i * 32;
            int r = row0g + lr;
            if (r < N_NODES) {
                *(float4*)&outf[(size_t)r * 64 + c8]     = *(const float4*)&sCf[lr * SC2F + c8];
                *(float4*)&outf[(size_t)r * 64 + c8 + 4] = *(const float4*)&sCf[lr * SC2F + c8 + 4];
            }
        }
    }
}

// ============================ launch ============================

extern "C" void kernel_launch(void* const* d_in, const int* in_sizes, int n_in,
                              void* d_out, int out_size, void* d_ws, size_t ws_size,
                              hipStream_t stream) {
    const float* x     = (const float*)d_in[0];
    const int*   ei    = (const int*)d_in[1];
    const float* W1    = (const float*)d_in[2];
    const float* b1    = (const float*)d_in[3];
    const float* gamma = (const float*)d_in[4];
    const float* beta  = (const float*)d_in[5];
    const float* W2    = (const float*)d_in[6];
    const float* b2    = (const float*)d_in[7];
    float* out = (float*)d_out;

    const int* src = ei;
    const int* dst = ei + N_EDGES;

    char* base = (char*)d_ws;
    size_t o = 0;
    auto take = [&](size_t bytes) -> char* {
        char* p = base + o;
        o = (o + bytes + 255) & ~(size_t)255;
        return p;
    };
    int* deg     = (int*)take((size_t)N_NODES * 4);
    int* off     = (int*)take((size_t)(N_NODES + 1) * 4);
    int* esrc    = (int*)take((size_t)(N_EDGES + 16) * 4);   // +16 pad (zeroed)
    u32* ebuf    = (u32*)take((size_t)N_EDGES * 4);          // packed (src<<16)|dst
    int* bsum    = (int*)take((size_t)N_SB * 4);
    int* boff    = (int*)take((size_t)N_SB * 4);
    int* gcur    = (int*)take((size_t)NB * 4);
    float* bn    = (float*)take(1024 * 4);  // per layer: S[128] Q[128]
    u16* w1f     = (u16*)take((size_t)4 * 8192 * 2);  // W1 frags, 4 layers
    u16* w2f     = (u16*)take((size_t)4 * 8192 * 2);  // W2 frags, 4 layers
    u16* xbuf    = (u16*)take((size_t)N_NODES * D_IN * 2);   // bf16 hidden state
    u16* rbuf    = (u16*)take((size_t)N_NODES * D_IN * 2);   // bf16 relu(state)
    u16* hbuf    = (u16*)take((size_t)N_NODES * D_IN * 2);   // bf16 agg output
    u16* h1buf   = (u16*)take((size_t)N_NODES * D_HID * 2);  // bf16 mid activations

    // CSR build (once per call; dst is layer-invariant)
    hipMemsetAsync(deg, 0, (size_t)N_NODES * 4, stream);
    count_kernel<<<(N_EDGES + 255) / 256, 256, 0, stream>>>(dst, deg, bn, esrc);
    scan_reduce_kernel<<<N_SB, SCAN_B, 0, stream>>>(deg, bsum);
    scan_sums_kernel<<<1, SCAN_B, 0, stream>>>(bsum, boff);
    scan_write_kernel<<<N_SB, SCAN_B, 0, stream>>>(deg, boff, off, gcur);
    bin_pass1_kernel<<<P1_BLOCKS, 256, 0, stream>>>(src, dst, gcur, ebuf);
    p2xw_kernel<<<NB + XCVT_B + 8, 256, 0, stream>>>(off, ebuf, esrc,
                                                     x, xbuf, rbuf,
                                                     W1, W2, w1f, w2f);

    const int NBLK = (N_NODES + 63) / 64;
    const int ABLK = (N_NODES + 3) / 4;  // 1 node/wave, 4 waves/block
    for (int L = 0; L < 4; L++) {
        float* Sb = bn + L * 256;
        float* Qb = Sb + 128;
        agg_kernel<<<ABLK, 256, 0, stream>>>(xbuf, rbuf, off, esrc, hbuf);
        gemm1_kernel<<<NBLK, 256, 0, stream>>>(
            hbuf, w1f + (size_t)L * 8192, b1 + (size_t)L * D_HID, h1buf,
            Sb, Qb);
        gemm2_kernel<<<NBLK, 256, 0, stream>>>(
            h1buf, Sb, Qb, gamma + (size_t)L * D_HID, beta + (size_t)L * D_HID,
            w2f + (size_t)L * 8192, b2 + (size_t)L * D_IN,
            out, xbuf, rbuf, (L < 3) ? 1 : 0);
    }
}

// Round 10
// 386.017 us; speedup vs baseline: 1.0301x; 1.0301x over previous
//
#include <hip/hip_runtime.h>
#include <math.h>

#define N_NODES 50000
#define N_EDGES 800000
#define D_IN 64
#define D_HID 128
#define SCAN_B 256
#define N_SB ((N_NODES + SCAN_B - 1) / SCAN_B)  // 196
#define NPB 256                                  // nodes per bucket
#define NB ((N_NODES + NPB - 1) / NPB)           // 196 buckets
#define P1_BLOCKS 256
#define EPB (N_EDGES / P1_BLOCKS)                // 3125 edges per pass-1 block
#define CAP 8192                                 // padded bucket capacity (mean 4096, sigma 64)
#define XCVT_B (N_NODES * D_IN / 4 / 256)        // 3125 blocks for xcvt part

typedef unsigned short u16;
typedef unsigned int u32;
typedef __attribute__((ext_vector_type(8))) short short8;
typedef __attribute__((ext_vector_type(4))) float f32x4;

union U4S8 { uint4 u; short8 s; };

__device__ __forceinline__ float bf2f(u16 u) {
    u32 x = ((u32)u) << 16;
    float f; __builtin_memcpy(&f, &x, 4); return f;
}
__device__ __forceinline__ u16 f2bf(float f) {  // round-to-nearest-even
    u32 x; __builtin_memcpy(&x, &f, 4);
    x += 0x7fffu + ((x >> 16) & 1u);
    return (u16)(x >> 16);
}
__device__ __forceinline__ u32 pk2(float a, float b) {  // pack 2 bf16 into u32
    return (u32)f2bf(a) | ((u32)f2bf(b) << 16);
}
// relu on 2 packed bf16 (zero halves with sign bit set) — branchless
__device__ __forceinline__ u32 relu2(u32 w) {
    u32 b = (w >> 15) & 0x00010001u;
    u32 m01 = b ^ 0x00010001u;        // 1 per half to KEEP
    u32 M = (m01 << 16) - m01;        // 0xFFFF per kept half
    return w & M;
}

// ============== CSR build: fused count + binned scatter pass 1 ==============
// Padded bucket-major ebuf[NB][CAP] breaks the scan dependency: pass1 needs
// only zeroed bcnt. deg counting (was count_kernel) fused into the hist loop
// -> one full dst pass and one dispatch removed. Block 0 zeroes bn + esrc pad.
__global__ __launch_bounds__(256) void bin_pass1_kernel(const int* __restrict__ src,
                                                        const int* __restrict__ dst,
                                                        int* __restrict__ deg,
                                                        int* __restrict__ bcnt,
                                                        u32* __restrict__ ebuf,
                                                        float* __restrict__ bn,
                                                        int* __restrict__ esrc) {
    __shared__ int hist[NB];
    __shared__ int base[NB];
    const int tid = threadIdx.x;
    const int e0 = blockIdx.x * EPB, e1 = e0 + EPB;
    for (int b = tid; b < NB; b += 256) hist[b] = 0;
    if (blockIdx.x == 0) {
        ((float4*)bn)[tid] = make_float4(0.f, 0.f, 0.f, 0.f);  // 256*4 = 1024
        if (tid < 16) esrc[N_EDGES + tid] = 0;
    }
    __syncthreads();
    for (int i = e0 + tid; i < e1; i += 256) {
        int d = dst[i];
        atomicAdd(&deg[d], 1);           // degree count (was count_kernel)
        atomicAdd(&hist[d >> 8], 1);
    }
    __syncthreads();
    for (int b = tid; b < NB; b += 256) {
        base[b] = atomicAdd(&bcnt[b], hist[b]);
        hist[b] = 0;  // reuse as block-local cursor
    }
    __syncthreads();
    for (int i = e0 + tid; i < e1; i += 256) {
        int d = dst[i];
        int b = d >> 8;
        int slot = base[b] + atomicAdd(&hist[b], 1);
        ebuf[(size_t)b * CAP + slot] = ((u32)src[i] << 16) | (u32)d;
    }
}

__global__ __launch_bounds__(SCAN_B) void scan_reduce_kernel(const int* __restrict__ deg,
                                                             int* __restrict__ bsum) {
    __shared__ int s[SCAN_B];
    int i = blockIdx.x * SCAN_B + threadIdx.x;
    int v = (i < N_NODES) ? deg[i] : 0;
    s[threadIdx.x] = v;
    __syncthreads();
    #pragma unroll
    for (int o = SCAN_B / 2; o > 0; o >>= 1) {
        if (threadIdx.x < o) s[threadIdx.x] += s[threadIdx.x + o];
        __syncthreads();
    }
    if (threadIdx.x == 0) bsum[blockIdx.x] = s[0];
}

__global__ __launch_bounds__(SCAN_B) void scan_sums_kernel(const int* __restrict__ bsum,
                                                           int* __restrict__ boff) {
    __shared__ int s[SCAN_B];
    int t = threadIdx.x;
    int v = (t < N_SB) ? bsum[t] : 0;
    s[t] = v;
    __syncthreads();
    #pragma unroll
    for (int o = 1; o < SCAN_B; o <<= 1) {
        int u = (t >= o) ? s[t - o] : 0;
        __syncthreads();
        s[t] += u;
        __syncthreads();
    }
    if (t < N_SB) boff[t] = s[t] - v;  // exclusive
}

__global__ __launch_bounds__(SCAN_B) void scan_write_kernel(const int* __restrict__ deg,
                                                            const int* __restrict__ boff,
                                                            int* __restrict__ off) {
    __shared__ int s[SCAN_B];
    int t = threadIdx.x;
    int i = blockIdx.x * SCAN_B + t;
    int v = (i < N_NODES) ? deg[i] : 0;
    s[t] = v;
    __syncthreads();
    #pragma unroll
    for (int o = 1; o < SCAN_B; o <<= 1) {
        int u = (t >= o) ? s[t - o] : 0;
        __syncthreads();
        s[t] += u;
        __syncthreads();
    }
    int incl = s[t] + boff[blockIdx.x];
    if (i < N_NODES) off[i] = incl - v;
    if (i == N_NODES - 1) off[N_NODES] = incl;
}

// ============ pass 2 (bucket->node scatter) + xcvt + wprep, one launch ========
// blocks [0, NB): pass2; [NB, NB+XCVT_B): x->bf16; [NB+XCVT_B, +8): W frags.
__global__ __launch_bounds__(256) void p2xw_kernel(const int* __restrict__ off,
                                                   const int* __restrict__ bcnt,
                                                   const u32* __restrict__ ebuf,
                                                   int* __restrict__ esrc,
                                                   const float* __restrict__ x,
                                                   u16* __restrict__ xb,
                                                   u16* __restrict__ rb,
                                                   const float* __restrict__ W1,
                                                   const float* __restrict__ W2,
                                                   u16* __restrict__ w1f,
                                                   u16* __restrict__ w2f) {
    const int tid = threadIdx.x;
    if (blockIdx.x < NB) {
        __shared__ int soff[NPB];
        __shared__ int cur[NPB];
        const int b = blockIdx.x;
        const int n0 = b * NPB;
        soff[tid] = off[min(n0 + tid, N_NODES)];
        cur[tid] = 0;
        __syncthreads();
        const int cnt = bcnt[b];
        const u32* eb = ebuf + (size_t)b * CAP;
        for (int i = tid; i < cnt; i += 256) {
            u32 p = eb[i];
            int dl = (int)(p & 0xFFFFu) - n0;
            int slot = soff[dl] + atomicAdd(&cur[dl], 1);
            esrc[slot] = (int)(p >> 16);
        }
        return;
    }
    if (blockIdx.x < NB + XCVT_B) {
        int i = (blockIdx.x - NB) * 256 + tid;  // one float4 per thread
        float4 v = ((const float4*)x)[i];
        u32 lo = pk2(v.x, v.y), hi = pk2(v.z, v.w);
        ((uint2*)xb)[i] = make_uint2(lo, hi);
        ((uint2*)rb)[i] = make_uint2(relu2(lo), relu2(hi));
        return;
    }
    const int b = blockIdx.x - NB - XCVT_B;  // 0..7: layer*2 + (0=W1, 1=W2)
    const int L = b >> 1;
    if ((b & 1) == 0) {
        const float* W = W1 + (size_t)L * 64 * 128;
        u16* outp = w1f + (size_t)L * 8192;
        for (int idx = tid; idx < 1024; idx += 256) {
            int ln = idx & 63, th = idx >> 6;          // th = t*2+half
            int half = th & 1, t = th >> 1;
            int k0 = half * 32 + (ln >> 4) * 8;
            int n = t * 16 + (ln & 15);
            uint4 o;
            o.x = pk2(W[(k0 + 0) * 128 + n], W[(k0 + 1) * 128 + n]);
            o.y = pk2(W[(k0 + 2) * 128 + n], W[(k0 + 3) * 128 + n]);
            o.z = pk2(W[(k0 + 4) * 128 + n], W[(k0 + 5) * 128 + n]);
            o.w = pk2(W[(k0 + 6) * 128 + n], W[(k0 + 7) * 128 + n]);
            *(uint4*)&outp[(size_t)idx * 8] = o;
        }
    } else {
        const float* W = W2 + (size_t)L * 128 * 64;
        u16* outp = w2f + (size_t)L * 8192;
        for (int idx = tid; idx < 1024; idx += 256) {
            int ln = idx & 63, th = idx >> 6;          // th = t*4+ks
            int ks = th & 3, t = th >> 2;
            int k0 = ks * 32 + (ln >> 4) * 8;
            int n = t * 16 + (ln & 15);
            uint4 o;
            o.x = pk2(W[(k0 + 0) * 64 + n], W[(k0 + 1) * 64 + n]);
            o.y = pk2(W[(k0 + 2) * 64 + n], W[(k0 + 3) * 64 + n]);
            o.z = pk2(W[(k0 + 4) * 64 + n], W[(k0 + 5) * 64 + n]);
            o.w = pk2(W[(k0 + 6) * 64 + n], W[(k0 + 7) * 64 + n]);
            *(uint4*)&outp[(size_t)idx * 8] = o;
        }
    }
}

// ==================== softmax aggregation + residual (bf16 in/out) ============
// lane = channel (64 channels). One wave per node, edges serial with 16 row
// loads in flight. esrc indices are wave-uniform -> SGPR loads. No cross-lane
// reduction, no divergent tail (one branchless masked iteration). [R8-verified]
__global__ __launch_bounds__(256) void agg_kernel(const u16* __restrict__ xb,
                                                  const u16* __restrict__ rb,
                                                  const int* __restrict__ off,
                                                  const int* __restrict__ esrc,
                                                  u16* __restrict__ h) {
    const int node = blockIdx.x * 4 + (threadIdx.x >> 6);
    const int ln = threadIdx.x & 63;
    const int jb = __builtin_amdgcn_readfirstlane(off[node]);
    const int je = __builtin_amdgcn_readfirstlane(off[node + 1]);
    const float xown = bf2f(xb[(size_t)node * 64 + ln]);  // residual, hoisted
    float s0 = 0.f, s1 = 0.f, t0 = 0.f, t1 = 0.f;
    int j = jb;
    const int nfull = (je - jb) >> 4;
    for (int it = 0; it < nfull; ++it, j += 16) {
        #pragma unroll
        for (int kk = 0; kk < 16; kk += 2) {
            int i0 = esrc[j + kk];        // SGPR load (uniform)
            int i1 = esrc[j + kk + 1];
            float m0 = bf2f(rb[(size_t)i0 * 64 + ln]);  // >= 0 already
            float m1 = bf2f(rb[(size_t)i1 * 64 + ln]);
            float p0 = __expf(m0);
            float p1 = __expf(m1);
            s0 += p0; t0 = fmaf(m0, p0, t0);
            s1 += p1; t1 = fmaf(m1, p1, t1);
        }
    }
    const int rem = je - j;               // 0..15
    if (rem > 0) {                        // one branchless masked iteration
        #pragma unroll
        for (int kk = 0; kk < 16; kk += 2) {
            int i0 = esrc[j + kk];        // padding is zeroed -> safe
            int i1 = esrc[j + kk + 1];
            float m0 = bf2f(rb[(size_t)i0 * 64 + ln]);
            float m1 = bf2f(rb[(size_t)i1 * 64 + ln]);
            float p0 = (kk < rem)     ? __expf(m0) : 0.f;
            float p1 = (kk + 1 < rem) ? __expf(m1) : 0.f;
            s0 += p0; t0 = fmaf(m0, p0, t0);
            s1 += p1; t1 = fmaf(m1, p1, t1);
        }
    }
    const float s = s0 + s1, t = t0 + t1;
    // eps-cancellation: exp(r+eps)=e^eps*exp(r) cancels in t/s; add eps once.
    const float v = t / (s + 1e-16f) + 1e-7f + xown;
    h[(size_t)node * 64 + ln] = f2bf(v);
}

// ==================== GEMM1 (MFMA) + LDS-transpose epilogue + BN stats ========
#define SC1 136  // u16 stride: 272 B = 17*16B (aligned for uint4 readback)
__global__ __launch_bounds__(256) void gemm1_kernel(const u16* __restrict__ A,
                                                    const u16* __restrict__ Wf,
                                                    const float* __restrict__ bias,
                                                    u16* __restrict__ Bout,
                                                    float* __restrict__ S,
                                                    float* __restrict__ Q) {
    __shared__ u16 sC[64 * SC1];          // 17.4 KB
    __shared__ float sRed[2][4][128];     // 4 KB: [S/Q][wave][channel]
    const int tid = threadIdx.x;
    const int wave = tid >> 6, ln = tid & 63;
    const int lm = ln & 15, quad = ln >> 4;
    const int row0g = blockIdx.x * 64;
    const int row0 = row0g + wave * 16;
    const int rA = min(row0 + lm, N_NODES - 1);

    // A-frags: A[m=lm][k=quad*8+j], two K=32 halves
    U4S8 a0, a1;
    a0.u = *(const uint4*)&A[(size_t)rA * 64 + quad * 8];
    a1.u = *(const uint4*)&A[(size_t)rA * 64 + 32 + quad * 8];

    f32x4 acc[8];
    #pragma unroll
    for (int t = 0; t < 8; t++) {
        float b = bias[t * 16 + lm];
        acc[t] = (f32x4){b, b, b, b};
    }
    #pragma unroll
    for (int t = 0; t < 8; t++) {
        U4S8 b0, b1;
        b0.u = *(const uint4*)&Wf[(size_t)((t * 2 + 0) * 64 + ln) * 8];
        b1.u = *(const uint4*)&Wf[(size_t)((t * 2 + 1) * 64 + ln) * 8];
        acc[t] = __builtin_amdgcn_mfma_f32_16x16x32_bf16(a0.s, b0.s, acc[t], 0, 0, 0);
        acc[t] = __builtin_amdgcn_mfma_f32_16x16x32_bf16(a1.s, b1.s, acc[t], 0, 0, 0);
    }
    // BN partial stats from registers (C layout: row = quad*4+rg, col = t*16+lm)
    const int rbase = row0 + quad * 4;
    #pragma unroll
    for (int t = 0; t < 8; t++) {
        float ss = 0.f, qq = 0.f;
        #pragma unroll
        for (int rg = 0; rg < 4; rg++) {
            if (rbase + rg < N_NODES) {
                float v = acc[t][rg];
                ss += v; qq = fmaf(v, v, qq);
            }
        }
        ss += __shfl_xor(ss, 16); ss += __shfl_xor(ss, 32);
        qq += __shfl_xor(qq, 16); qq += __shfl_xor(qq, 32);
        if (quad == 0) {
            sRed[0][wave][t * 16 + lm] = ss;
            sRed[1][wave][t * 16 + lm] = qq;
        }
    }
    // transpose through LDS (C-layout -> row-major bf16 tile)
    const int lr0 = wave * 16 + quad * 4;
    #pragma unroll
    for (int t = 0; t < 8; t++) {
        #pragma unroll
        for (int rg = 0; rg < 4; rg++)
            sC[(lr0 + rg) * SC1 + t * 16 + lm] = f2bf(acc[t][rg]);
    }
    __syncthreads();
    // coalesced vectorized store
    const int c8 = (tid & 15) * 8;
    #pragma unroll
    for (int i = 0; i < 4; i++) {
        int lr = (tid >> 4) + i * 16;
        int r = row0g + lr;
        if (r < N_NODES)
            *(uint4*)&Bout[(size_t)r * 128 + c8] = *(const uint4*)&sC[lr * SC1 + c8];
    }
    // one atomic per column per block (cross-wave sums from sRed)
    if (tid < 128) {
        float v = sRed[0][0][tid] + sRed[0][1][tid] + sRed[0][2][tid] + sRed[0][3][tid];
        atomicAdd(&S[tid], v);
    } else {
        int c = tid - 128;
        float v = sRed[1][0][c] + sRed[1][1][c] + sRed[1][2][c] + sRed[1][3][c];
        atomicAdd(&Q[c], v);
    }
}

// ==================== GEMM2 (MFMA) + fused BN finalize + LDS epilogue =========
__device__ __forceinline__ float mish_f(float v) {
    if (v > 30.f) return v;
    float u = __expf(v);
    float t = (u + 1.f) * (u + 1.f);
    return v * (t - 1.f) / (t + 1.f);  // = v * tanh(softplus(v))
}

#define SC2B 72  // u16 stride for bf16 tile: 144 B = 9*16B
#define SC2F 68  // f32 stride for fp32 tile: 272 B = 17*16B
__global__ __launch_bounds__(256) void gemm2_kernel(const u16* __restrict__ H,
                                                    const float* __restrict__ S,
                                                    const float* __restrict__ Q,
                                                    const float* __restrict__ gamma,
                                                    const float* __restrict__ beta,
                                                    const u16* __restrict__ Wf,
                                                    const float* __restrict__ bias,
                                                    float* __restrict__ outf,
                                                    u16* __restrict__ xb,
                                                    u16* __restrict__ rb,
                                                    int dobf16) {
    __shared__ float sss[256];
    __shared__ __align__(16) char sCraw[64 * SC2F * 4];  // 17.4 KB
    u16* sCb = (u16*)sCraw;
    float* sCf = (float*)sCraw;
    const int tid = threadIdx.x;
    // fused BN finalize: per-channel scale/shift from global S/Q
    if (tid < 128) {
        float mean = S[tid] * (1.f / N_NODES);
        float var = fmaxf(Q[tid] * (1.f / N_NODES) - mean * mean, 0.f);
        float sc = gamma[tid] * rsqrtf(var + 1e-5f);
        sss[tid] = sc;
        sss[128 + tid] = beta[tid] - mean * sc;
    }
    __syncthreads();
    const int wave = tid >> 6, ln = tid & 63;
    const int lm = ln & 15, quad = ln >> 4;
    const int row0g = blockIdx.x * 64;
    const int row0 = row0g + wave * 16;
    const int rA = min(row0 + lm, N_NODES - 1);

    f32x4 acc[4];
    #pragma unroll
    for (int t = 0; t < 4; t++) {
        float b = bias[t * 16 + lm];
        acc[t] = (f32x4){b, b, b, b};
    }
    #pragma unroll
    for (int ks = 0; ks < 4; ks++) {
        const int k0 = ks * 32 + quad * 8;
        U4S8 h8;
        h8.u = *(const uint4*)&H[(size_t)rA * 128 + k0];
        U4S8 a;
        #pragma unroll
        for (int j2 = 0; j2 < 4; j2++) {
            int k = k0 + 2 * j2;
            float v0 = fmaxf(fmaf(bf2f((u16)h8.s[2 * j2]),     sss[k],     sss[128 + k]),     0.f);
            float v1 = fmaxf(fmaf(bf2f((u16)h8.s[2 * j2 + 1]), sss[k + 1], sss[128 + k + 1]), 0.f);
            ((u32*)&a.u)[j2] = pk2(v0, v1);
        }
        #pragma unroll
        for (int t = 0; t < 4; t++) {
            U4S8 b;
            b.u = *(const uint4*)&Wf[(size_t)((t * 4 + ks) * 64 + ln) * 8];
            acc[t] = __builtin_amdgcn_mfma_f32_16x16x32_bf16(a.s, b.s, acc[t], 0, 0, 0);
        }
    }
    const int lr0 = wave * 16 + quad * 4;
    if (dobf16) {
        #pragma unroll
        for (int t = 0; t < 4; t++) {
            #pragma unroll
            for (int rg = 0; rg < 4; rg++)
                sCb[(lr0 + rg) * SC2B + t * 16 + lm] = f2bf(mish_f(acc[t][rg]));
        }
        __syncthreads();
        const int c8 = (tid & 7) * 8;
        #pragma unroll
        for (int i = 0; i < 2; i++) {
            int lr = (tid >> 3) + i * 32;
            int r = row0g + lr;
            if (r < N_NODES) {
                uint4 val = *(const uint4*)&sCb[lr * SC2B + c8];
                *(uint4*)&xb[(size_t)r * 64 + c8] = val;
                uint4 rv;
                rv.x = relu2(val.x); rv.y = relu2(val.y);
                rv.z = relu2(val.z); rv.w = relu2(val.w);
                *(uint4*)&rb[(size_t)r * 64 + c8] = rv;
            }
        }
    } else {
        #pragma unroll
        for (int t = 0; t < 4; t++) {
            #pragma unroll
            for (int rg = 0; rg < 4; rg++)
                sCf[(lr0 + rg) * SC2F + t * 16 + lm] = acc[t][rg];
        }
        __syncthreads();
        const int c8 = (tid & 7) * 8;
        #pragma unroll
        for (int i = 0; i < 2; i++) {
            int lr = (tid >> 3) + i * 32;
            int r = row0g + lr;
            if (r < N_NODES) {
                *(float4*)&outf[(size_t)r * 64 + c8]     = *(const float4*)&sCf[lr * SC2F + c8];
                *(float4*)&outf[(size_t)r * 64 + c8 + 4] = *(const float4*)&sCf[lr * SC2F + c8 + 4];
            }
        }
    }
}

// ============================ launch ============================

extern "C" void kernel_launch(void* const* d_in, const int* in_sizes, int n_in,
                              void* d_out, int out_size, void* d_ws, size_t ws_size,
                              hipStream_t stream) {
    const float* x     = (const float*)d_in[0];
    const int*   ei    = (const int*)d_in[1];
    const float* W1    = (const float*)d_in[2];
    const float* b1    = (const float*)d_in[3];
    const float* gamma = (const float*)d_in[4];
    const float* beta  = (const float*)d_in[5];
    const float* W2    = (const float*)d_in[6];
    const float* b2    = (const float*)d_in[7];
    float* out = (float*)d_out;

    const int* src = ei;
    const int* dst = ei + N_EDGES;

    char* base = (char*)d_ws;
    size_t o = 0;
    auto take = [&](size_t bytes) -> char* {
        char* p = base + o;
        o = (o + bytes + 255) & ~(size_t)255;
        return p;
    };
    int* deg     = (int*)take((size_t)(N_NODES + NB) * 4);   // deg + bcnt (one memset)
    int* bcnt    = deg + N_NODES;
    int* off     = (int*)take((size_t)(N_NODES + 1) * 4);
    int* esrc    = (int*)take((size_t)(N_EDGES + 16) * 4);   // +16 pad (zeroed)
    u32* ebuf    = (u32*)take((size_t)NB * CAP * 4);         // padded bucket-major
    int* bsum    = (int*)take((size_t)N_SB * 4);
    int* boff    = (int*)take((size_t)N_SB * 4);
    float* bn    = (float*)take(1024 * 4);  // per layer: S[128] Q[128]
    u16* w1f     = (u16*)take((size_t)4 * 8192 * 2);  // W1 frags, 4 layers
    u16* w2f     = (u16*)take((size_t)4 * 8192 * 2);  // W2 frags, 4 layers
    u16* xbuf    = (u16*)take((size_t)N_NODES * D_IN * 2);   // bf16 hidden state
    u16* rbuf    = (u16*)take((size_t)N_NODES * D_IN * 2);   // bf16 relu(state)
    u16* hbuf    = (u16*)take((size_t)N_NODES * D_IN * 2);   // bf16 agg output
    u16* h1buf   = (u16*)take((size_t)N_NODES * D_HID * 2);  // bf16 mid activations

    // CSR build (once per call; dst is layer-invariant)
    hipMemsetAsync(deg, 0, (size_t)(N_NODES + NB) * 4, stream);
    bin_pass1_kernel<<<P1_BLOCKS, 256, 0, stream>>>(src, dst, deg, bcnt, ebuf, bn, esrc);
    scan_reduce_kernel<<<N_SB, SCAN_B, 0, stream>>>(deg, bsum);
    scan_sums_kernel<<<1, SCAN_B, 0, stream>>>(bsum, boff);
    scan_write_kernel<<<N_SB, SCAN_B, 0, stream>>>(deg, boff, off);
    p2xw_kernel<<<NB + XCVT_B + 8, 256, 0, stream>>>(off, bcnt, ebuf, esrc,
                                                     x, xbuf, rbuf,
                                                     W1, W2, w1f, w2f);

    const int NBLK = (N_NODES + 63) / 64;
    const int ABLK = (N_NODES + 3) / 4;  // 1 node/wave, 4 waves/block
    for (int L = 0; L < 4; L++) {
        float* Sb = bn + L * 256;
        float* Qb = Sb + 128;
        agg_kernel<<<ABLK, 256, 0, stream>>>(xbuf, rbuf, off, esrc, hbuf);
        gemm1_kernel<<<NBLK, 256, 0, stream>>>(
            hbuf, w1f + (size_t)L * 8192, b1 + (size_t)L * D_HID, h1buf,
            Sb, Qb);
        gemm2_kernel<<<NBLK, 256, 0, stream>>>(
            h1buf, Sb, Qb, gamma + (size_t)L * D_HID, beta + (size_t)L * D_HID,
            w2f + (size_t)L * 8192, b2 + (size_t)L * D_IN,
            out, xbuf, rbuf, (L < 3) ? 1 : 0);
    }
}

// Round 11
// 349.888 us; speedup vs baseline: 1.1364x; 1.1033x over previous
//
#include <hip/hip_runtime.h>
#include <math.h>

#define N_NODES 50000
#define N_EDGES 800000
#define D_IN 64
#define D_HID 128
#define NPB 256                                  // nodes per bucket
#define NB ((N_NODES + NPB - 1) / NPB)           // 196 buckets
#define P1_BLOCKS 800
#define EPB (N_EDGES / P1_BLOCKS)                // 1000 edges per pass-1 block
#define CAP 8192                                 // padded bucket capacity (mean ~4082, sigma ~64)
#define BCS 32                                   // bcnt stride (ints) = 1 cache line/bucket
#define XCVT_B (N_NODES * D_IN / 4 / 256)        // 3125 blocks for xcvt part

typedef unsigned short u16;
typedef unsigned int u32;
typedef __attribute__((ext_vector_type(8))) short short8;
typedef __attribute__((ext_vector_type(4))) float f32x4;

union U4S8 { uint4 u; short8 s; };

__device__ __forceinline__ float bf2f(u16 u) {
    u32 x = ((u32)u) << 16;
    float f; __builtin_memcpy(&f, &x, 4); return f;
}
__device__ __forceinline__ u16 f2bf(float f) {  // round-to-nearest-even
    u32 x; __builtin_memcpy(&x, &f, 4);
    x += 0x7fffu + ((x >> 16) & 1u);
    return (u16)(x >> 16);
}
__device__ __forceinline__ u32 pk2(float a, float b) {  // pack 2 bf16 into u32
    return (u32)f2bf(a) | ((u32)f2bf(b) << 16);
}
// relu on 2 packed bf16 (zero halves with sign bit set) — branchless
__device__ __forceinline__ u32 relu2(u32 w) {
    u32 b = (w >> 15) & 0x00010001u;
    u32 m01 = b ^ 0x00010001u;        // 1 per half to KEEP
    u32 M = (m01 << 16) - m01;        // 0xFFFF per kept half
    return w & M;
}

// ============== CSR build: binned scatter pass 1 (no deg, no scan) ==========
// Padded bucket-major ebuf[NB][CAP]; bcnt padded 1 line/bucket to spread the
// reservation atomics. 800 blocks (3/CU) hide atomic + scattered-write latency.
// Block 0 zeroes bn + esrc tail pad. Global node offsets are derived in pass2
// from bcnt prefix (off = sum of earlier buckets) — deg[] and the 3-kernel
// scan chain are deleted.
__global__ __launch_bounds__(256) void bin_pass1_kernel(const int* __restrict__ src,
                                                        const int* __restrict__ dst,
                                                        int* __restrict__ bcnt,
                                                        u32* __restrict__ ebuf,
                                                        float* __restrict__ bn,
                                                        int* __restrict__ esrc) {
    __shared__ int hist[NB];
    __shared__ int base[NB];
    const int tid = threadIdx.x;
    const int e0 = blockIdx.x * EPB, e1 = e0 + EPB;
    for (int b = tid; b < NB; b += 256) hist[b] = 0;
    if (blockIdx.x == 0) {
        ((float4*)bn)[tid] = make_float4(0.f, 0.f, 0.f, 0.f);  // 256*4 = 1024
        if (tid < 16) esrc[N_EDGES + tid] = 0;
    }
    __syncthreads();
    for (int i = e0 + tid; i < e1; i += 256)
        atomicAdd(&hist[dst[i] >> 8], 1);
    __syncthreads();
    for (int b = tid; b < NB; b += 256) {
        base[b] = atomicAdd(&bcnt[b * BCS], hist[b]);
        hist[b] = 0;  // reuse as block-local cursor
    }
    __syncthreads();
    for (int i = e0 + tid; i < e1; i += 256) {
        int d = dst[i];
        int b = d >> 8;
        int slot = base[b] + atomicAdd(&hist[b], 1);
        ebuf[(size_t)b * CAP + slot] = ((u32)src[i] << 16) | (u32)d;
    }
}

// ====== pass 2 (bucket->CSR, computes off itself) + xcvt + wprep, one launch ==
// blocks [0, NB): pass2; [NB, NB+XCVT_B): x->bf16; [NB+XCVT_B, +8): W frags.
__global__ __launch_bounds__(256) void p2xw_kernel(int* __restrict__ off,
                                                   const int* __restrict__ bcnt,
                                                   const u32* __restrict__ ebuf,
                                                   int* __restrict__ esrc,
                                                   const float* __restrict__ x,
                                                   u16* __restrict__ xb,
                                                   u16* __restrict__ rb,
                                                   const float* __restrict__ W1,
                                                   const float* __restrict__ W2,
                                                   u16* __restrict__ w1f,
                                                   u16* __restrict__ w2f) {
    const int tid = threadIdx.x;
    if (blockIdx.x < NB) {
        __shared__ int s[NPB];      // reduce/scan temp
        __shared__ int sdeg[NPB];   // local degree, later reused as cursor
        __shared__ int soff[NPB];   // global node offsets
        const int b = blockIdx.x;
        const int n0 = b * NPB;
        // global base = sum of bcnt[t] for t < b   (b <= 195 < 256)
        s[tid] = (tid < b) ? bcnt[tid * BCS] : 0;
        sdeg[tid] = 0;
        __syncthreads();
        #pragma unroll
        for (int o = 128; o > 0; o >>= 1) {
            if (tid < o) s[tid] += s[tid + o];
            __syncthreads();
        }
        const int sbase = s[0];
        const int cnt = bcnt[b * BCS];
        const u32* eb = ebuf + (size_t)b * CAP;
        // local degree count (L2-hot re-read later for scatter)
        for (int i = tid; i < cnt; i += 256)
            atomicAdd(&sdeg[(int)(eb[i] & 0xFFFFu) - n0], 1);
        __syncthreads();
        const int v = sdeg[tid];
        s[tid] = v;
        __syncthreads();
        #pragma unroll
        for (int o = 1; o < NPB; o <<= 1) {
            int u = (tid >= o) ? s[tid - o] : 0;
            __syncthreads();
            s[tid] += u;
            __syncthreads();
        }
        const int go = sbase + s[tid] - v;  // exclusive global offset
        soff[tid] = go;
        if (n0 + tid < N_NODES) off[n0 + tid] = go;
        if (b == 0 && tid == 0) off[N_NODES] = N_EDGES;
        sdeg[tid] = 0;                      // reuse as per-node cursor
        __syncthreads();
        for (int i = tid; i < cnt; i += 256) {
            u32 p = eb[i];
            int dl = (int)(p & 0xFFFFu) - n0;
            int slot = soff[dl] + atomicAdd(&sdeg[dl], 1);
            esrc[slot] = (int)(p >> 16);
        }
        return;
    }
    if (blockIdx.x < NB + XCVT_B) {
        int i = (blockIdx.x - NB) * 256 + tid;  // one float4 per thread
        float4 v = ((const float4*)x)[i];
        u32 lo = pk2(v.x, v.y), hi = pk2(v.z, v.w);
        ((uint2*)xb)[i] = make_uint2(lo, hi);
        ((uint2*)rb)[i] = make_uint2(relu2(lo), relu2(hi));
        return;
    }
    const int b = blockIdx.x - NB - XCVT_B;  // 0..7: layer*2 + (0=W1, 1=W2)
    const int L = b >> 1;
    if ((b & 1) == 0) {
        const float* W = W1 + (size_t)L * 64 * 128;
        u16* outp = w1f + (size_t)L * 8192;
        for (int idx = tid; idx < 1024; idx += 256) {
            int ln = idx & 63, th = idx >> 6;          // th = t*2+half
            int half = th & 1, t = th >> 1;
            int k0 = half * 32 + (ln >> 4) * 8;
            int n = t * 16 + (ln & 15);
            uint4 o;
            o.x = pk2(W[(k0 + 0) * 128 + n], W[(k0 + 1) * 128 + n]);
            o.y = pk2(W[(k0 + 2) * 128 + n], W[(k0 + 3) * 128 + n]);
            o.z = pk2(W[(k0 + 4) * 128 + n], W[(k0 + 5) * 128 + n]);
            o.w = pk2(W[(k0 + 6) * 128 + n], W[(k0 + 7) * 128 + n]);
            *(uint4*)&outp[(size_t)idx * 8] = o;
        }
    } else {
        const float* W = W2 + (size_t)L * 128 * 64;
        u16* outp = w2f + (size_t)L * 8192;
        for (int idx = tid; idx < 1024; idx += 256) {
            int ln = idx & 63, th = idx >> 6;          // th = t*4+ks
            int ks = th & 3, t = th >> 2;
            int k0 = ks * 32 + (ln >> 4) * 8;
            int n = t * 16 + (ln & 15);
            uint4 o;
            o.x = pk2(W[(k0 + 0) * 64 + n], W[(k0 + 1) * 64 + n]);
            o.y = pk2(W[(k0 + 2) * 64 + n], W[(k0 + 3) * 64 + n]);
            o.z = pk2(W[(k0 + 4) * 64 + n], W[(k0 + 5) * 64 + n]);
            o.w = pk2(W[(k0 + 6) * 64 + n], W[(k0 + 7) * 64 + n]);
            *(uint4*)&outp[(size_t)idx * 8] = o;
        }
    }
}

// ==================== softmax aggregation + residual (bf16 in/out) ============
// lane = channel (64 channels). One wave per node, edges serial with 16 row
// loads in flight. esrc indices are wave-uniform -> SGPR loads. No cross-lane
// reduction, no divergent tail (one branchless masked iteration). [R8-verified]
__global__ __launch_bounds__(256) void agg_kernel(const u16* __restrict__ xb,
                                                  const u16* __restrict__ rb,
                                                  const int* __restrict__ off,
                                                  const int* __restrict__ esrc,
                                                  u16* __restrict__ h) {
    const int node = blockIdx.x * 4 + (threadIdx.x >> 6);
    const int ln = threadIdx.x & 63;
    const int jb = __builtin_amdgcn_readfirstlane(off[node]);
    const int je = __builtin_amdgcn_readfirstlane(off[node + 1]);
    const float xown = bf2f(xb[(size_t)node * 64 + ln]);  // residual, hoisted
    float s0 = 0.f, s1 = 0.f, t0 = 0.f, t1 = 0.f;
    int j = jb;
    const int nfull = (je - jb) >> 4;
    for (int it = 0; it < nfull; ++it, j += 16) {
        #pragma unroll
        for (int kk = 0; kk < 16; kk += 2) {
            int i0 = esrc[j + kk];        // SGPR load (uniform)
            int i1 = esrc[j + kk + 1];
            float m0 = bf2f(rb[(size_t)i0 * 64 + ln]);  // >= 0 already
            float m1 = bf2f(rb[(size_t)i1 * 64 + ln]);
            float p0 = __expf(m0);
            float p1 = __expf(m1);
            s0 += p0; t0 = fmaf(m0, p0, t0);
            s1 += p1; t1 = fmaf(m1, p1, t1);
        }
    }
    const int rem = je - j;               // 0..15
    if (rem > 0) {                        // one branchless masked iteration
        #pragma unroll
        for (int kk = 0; kk < 16; kk += 2) {
            int i0 = esrc[j + kk];        // padding is zeroed -> safe
            int i1 = esrc[j + kk + 1];
            float m0 = bf2f(rb[(size_t)i0 * 64 + ln]);
            float m1 = bf2f(rb[(size_t)i1 * 64 + ln]);
            float p0 = (kk < rem)     ? __expf(m0) : 0.f;
            float p1 = (kk + 1 < rem) ? __expf(m1) : 0.f;
            s0 += p0; t0 = fmaf(m0, p0, t0);
            s1 += p1; t1 = fmaf(m1, p1, t1);
        }
    }
    const float s = s0 + s1, t = t0 + t1;
    // eps-cancellation: exp(r+eps)=e^eps*exp(r) cancels in t/s; add eps once.
    const float v = t / (s + 1e-16f) + 1e-7f + xown;
    h[(size_t)node * 64 + ln] = f2bf(v);
}

// ==================== GEMM1 (MFMA) + LDS-transpose epilogue + BN stats ========
#define SC1 136  // u16 stride: 272 B = 17*16B (aligned for uint4 readback)
__global__ __launch_bounds__(256) void gemm1_kernel(const u16* __restrict__ A,
                                                    const u16* __restrict__ Wf,
                                                    const float* __restrict__ bias,
                                                    u16* __restrict__ Bout,
                                                    float* __restrict__ S,
                                                    float* __restrict__ Q) {
    __shared__ u16 sC[64 * SC1];          // 17.4 KB
    __shared__ float sRed[2][4][128];     // 4 KB: [S/Q][wave][channel]
    const int tid = threadIdx.x;
    const int wave = tid >> 6, ln = tid & 63;
    const int lm = ln & 15, quad = ln >> 4;
    const int row0g = blockIdx.x * 64;
    const int row0 = row0g + wave * 16;
    const int rA = min(row0 + lm, N_NODES - 1);

    // A-frags: A[m=lm][k=quad*8+j], two K=32 halves
    U4S8 a0, a1;
    a0.u = *(const uint4*)&A[(size_t)rA * 64 + quad * 8];
    a1.u = *(const uint4*)&A[(size_t)rA * 64 + 32 + quad * 8];

    f32x4 acc[8];
    #pragma unroll
    for (int t = 0; t < 8; t++) {
        float b = bias[t * 16 + lm];
        acc[t] = (f32x4){b, b, b, b};
    }
    #pragma unroll
    for (int t = 0; t < 8; t++) {
        U4S8 b0, b1;
        b0.u = *(const uint4*)&Wf[(size_t)((t * 2 + 0) * 64 + ln) * 8];
        b1.u = *(const uint4*)&Wf[(size_t)((t * 2 + 1) * 64 + ln) * 8];
        acc[t] = __builtin_amdgcn_mfma_f32_16x16x32_bf16(a0.s, b0.s, acc[t], 0, 0, 0);
        acc[t] = __builtin_amdgcn_mfma_f32_16x16x32_bf16(a1.s, b1.s, acc[t], 0, 0, 0);
    }
    // BN partial stats from registers (C layout: row = quad*4+rg, col = t*16+lm)
    const int rbase = row0 + quad * 4;
    #pragma unroll
    for (int t = 0; t < 8; t++) {
        float ss = 0.f, qq = 0.f;
        #pragma unroll
        for (int rg = 0; rg < 4; rg++) {
            if (rbase + rg < N_NODES) {
                float v = acc[t][rg];
                ss += v; qq = fmaf(v, v, qq);
            }
        }
        ss += __shfl_xor(ss, 16); ss += __shfl_xor(ss, 32);
        qq += __shfl_xor(qq, 16); qq += __shfl_xor(qq, 32);
        if (quad == 0) {
            sRed[0][wave][t * 16 + lm] = ss;
            sRed[1][wave][t * 16 + lm] = qq;
        }
    }
    // transpose through LDS (C-layout -> row-major bf16 tile)
    const int lr0 = wave * 16 + quad * 4;
    #pragma unroll
    for (int t = 0; t < 8; t++) {
        #pragma unroll
        for (int rg = 0; rg < 4; rg++)
            sC[(lr0 + rg) * SC1 + t * 16 + lm] = f2bf(acc[t][rg]);
    }
    __syncthreads();
    // coalesced vectorized store
    const int c8 = (tid & 15) * 8;
    #pragma unroll
    for (int i = 0; i < 4; i++) {
        int lr = (tid >> 4) + i * 16;
        int r = row0g + lr;
        if (r < N_NODES)
            *(uint4*)&Bout[(size_t)r * 128 + c8] = *(const uint4*)&sC[lr * SC1 + c8];
    }
    // one atomic per column per block (cross-wave sums from sRed)
    if (tid < 128) {
        float v = sRed[0][0][tid] + sRed[0][1][tid] + sRed[0][2][tid] + sRed[0][3][tid];
        atomicAdd(&S[tid], v);
    } else {
        int c = tid - 128;
        float v = sRed[1][0][c] + sRed[1][1][c] + sRed[1][2][c] + sRed[1][3][c];
        atomicAdd(&Q[c], v);
    }
}

// ==================== GEMM2 (MFMA) + fused BN finalize + LDS epilogue =========
__device__ __forceinline__ float mish_f(float v) {
    if (v > 30.f) return v;
    float u = __expf(v);
    float t = (u + 1.f) * (u + 1.f);
    return v * (t - 1.f) / (t + 1.f);  // = v * tanh(softplus(v))
}

#define SC2B 72  // u16 stride for bf16 tile: 144 B = 9*16B
#define SC2F 68  // f32 stride for fp32 tile: 272 B = 17*16B
__global__ __launch_bounds__(256) void gemm2_kernel(const u16* __restrict__ H,
                                                    const float* __restrict__ S,
                                                    const float* __restrict__ Q,
                                                    const float* __restrict__ gamma,
                                                    const float* __restrict__ beta,
                                                    const u16* __restrict__ Wf,
                                                    const float* __restrict__ bias,
                                                    float* __restrict__ outf,
                                                    u16* __restrict__ xb,
                                                    u16* __restrict__ rb,
                                                    int dobf16) {
    __shared__ float sss[256];
    __shared__ __align__(16) char sCraw[64 * SC2F * 4];  // 17.4 KB
    u16* sCb = (u16*)sCraw;
    float* sCf = (float*)sCraw;
    const int tid = threadIdx.x;
    // fused BN finalize: per-channel scale/shift from global S/Q
    if (tid < 128) {
        float mean = S[tid] * (1.f / N_NODES);
        float var = fmaxf(Q[tid] * (1.f / N_NODES) - mean * mean, 0.f);
        float sc = gamma[tid] * rsqrtf(var + 1e-5f);
        sss[tid] = sc;
        sss[128 + tid] = beta[tid] - mean * sc;
    }
    __syncthreads();
    const int wave = tid >> 6, ln = tid & 63;
    const int lm = ln & 15, quad = ln >> 4;
    const int row0g = blockIdx.x * 64;
    const int row0 = row0g + wave * 16;
    const int rA = min(row0 + lm, N_NODES - 1);

    f32x4 acc[4];
    #pragma unroll
    for (int t = 0; t < 4; t++) {
        float b = bias[t * 16 + lm];
        acc[t] = (f32x4){b, b, b, b};
    }
    #pragma unroll
    for (int ks = 0; ks < 4; ks++) {
        const int k0 = ks * 32 + quad * 8;
        U4S8 h8;
        h8.u = *(const uint4*)&H[(size_t)rA * 128 + k0];
        U4S8 a;
        #pragma unroll
        for (int j2 = 0; j2 < 4; j2++) {
            int k = k0 + 2 * j2;
            float v0 = fmaxf(fmaf(bf2f((u16)h8.s[2 * j2]),     sss[k],     sss[128 + k]),     0.f);
            float v1 = fmaxf(fmaf(bf2f((u16)h8.s[2 * j2 + 1]), sss[k + 1], sss[128 + k + 1]), 0.f);
            ((u32*)&a.u)[j2] = pk2(v0, v1);
        }
        #pragma unroll
        for (int t = 0; t < 4; t++) {
            U4S8 b;
            b.u = *(const uint4*)&Wf[(size_t)((t * 4 + ks) * 64 + ln) * 8];
            acc[t] = __builtin_amdgcn_mfma_f32_16x16x32_bf16(a.s, b.s, acc[t], 0, 0, 0);
        }
    }
    const int lr0 = wave * 16 + quad * 4;
    if (dobf16) {
        #pragma unroll
        for (int t = 0; t < 4; t++) {
            #pragma unroll
            for (int rg = 0; rg < 4; rg++)
                sCb[(lr0 + rg) * SC2B + t * 16 + lm] = f2bf(mish_f(acc[t][rg]));
        }
        __syncthreads();
        const int c8 = (tid & 7) * 8;
        #pragma unroll
        for (int i = 0; i < 2; i++) {
            int lr = (tid >> 3) + i * 32;
            int r = row0g + lr;
            if (r < N_NODES) {
                uint4 val = *(const uint4*)&sCb[lr * SC2B + c8];
                *(uint4*)&xb[(size_t)r * 64 + c8] = val;
                uint4 rv;
                rv.x = relu2(val.x); rv.y = relu2(val.y);
                rv.z = relu2(val.z); rv.w = relu2(val.w);
                *(uint4*)&rb[(size_t)r * 64 + c8] = rv;
            }
        }
    } else {
        #pragma unroll
        for (int t = 0; t < 4; t++) {
            #pragma unroll
            for (int rg = 0; rg < 4; rg++)
                sCf[(lr0 + rg) * SC2F + t * 16 + lm] = acc[t][rg];
        }
        __syncthreads();
        const int c8 = (tid & 7) * 8;
        #pragma unroll
        for (int i = 0; i < 2; i++) {
            int lr = (tid >> 3) + i * 32;
            int r = row0g + lr;
            if (r < N_NODES) {
                *(float4*)&outf[(size_t)r * 64 + c8]     = *(const float4*)&sCf[lr * SC2F + c8];
                *(float4*)&outf[(size_t)r * 64 + c8 + 4] = *(const float4*)&sCf[lr * SC2F + c8 + 4];
            }
        }
    }
}

// ============================ launch ============================

extern "C" void kernel_launch(void* const* d_in, const int* in_sizes, int n_in,
                              void* d_out, int out_size, void* d_ws, size_t ws_size,
                              hipStream_t stream) {
    const float* x     = (const float*)d_in[0];
    const int*   ei    = (const int*)d_in[1];
    const float* W1    = (const float*)d_in[2];
    const float* b1    = (const float*)d_in[3];
    const float* gamma = (const float*)d_in[4];
    const float* beta  = (const float*)d_in[5];
    const float* W2    = (const float*)d_in[6];
    const float* b2    = (const float*)d_in[7];
    float* out = (float*)d_out;

    const int* src = ei;
    const int* dst = ei + N_EDGES;

    char* base = (char*)d_ws;
    size_t o = 0;
    auto take = [&](size_t bytes) -> char* {
        char* p = base + o;
        o = (o + bytes + 255) & ~(size_t)255;
        return p;
    };
    int* bcnt    = (int*)take((size_t)NB * BCS * 4);         // padded cursors (memset)
    int* off     = (int*)take((size_t)(N_NODES + 1) * 4);
    int* esrc    = (int*)take((size_t)(N_EDGES + 16) * 4);   // +16 pad (zeroed)
    u32* ebuf    = (u32*)take((size_t)NB * CAP * 4);         // padded bucket-major
    float* bn    = (float*)take(1024 * 4);  // per layer: S[128] Q[128]
    u16* w1f     = (u16*)take((size_t)4 * 8192 * 2);  // W1 frags, 4 layers
    u16* w2f     = (u16*)take((size_t)4 * 8192 * 2);  // W2 frags, 4 layers
    u16* xbuf    = (u16*)take((size_t)N_NODES * D_IN * 2);   // bf16 hidden state
    u16* rbuf    = (u16*)take((size_t)N_NODES * D_IN * 2);   // bf16 relu(state)
    u16* hbuf    = (u16*)take((size_t)N_NODES * D_IN * 2);   // bf16 agg output
    u16* h1buf   = (u16*)take((size_t)N_NODES * D_HID * 2);  // bf16 mid activations

    // CSR build (once per call; dst is layer-invariant)
    hipMemsetAsync(bcnt, 0, (size_t)NB * BCS * 4, stream);
    bin_pass1_kernel<<<P1_BLOCKS, 256, 0, stream>>>(src, dst, bcnt, ebuf, bn, esrc);
    p2xw_kernel<<<NB + XCVT_B + 8, 256, 0, stream>>>(off, bcnt, ebuf, esrc,
                                                     x, xbuf, rbuf,
                                                     W1, W2, w1f, w2f);

    const int NBLK = (N_NODES + 63) / 64;
    const int ABLK = (N_NODES + 3) / 4;  // 1 node/wave, 4 waves/block
    for (int L = 0; L < 4; L++) {
        float* Sb = bn + L * 256;
        float* Qb = Sb + 128;
        agg_kernel<<<ABLK, 256, 0, stream>>>(xbuf, rbuf, off, esrc, hbuf);
        gemm1_kernel<<<NBLK, 256, 0, stream>>>(
            hbuf, w1f + (size_t)L * 8192, b1 + (size_t)L * D_HID, h1buf,
            Sb, Qb);
        gemm2_kernel<<<NBLK, 256, 0, stream>>>(
            h1buf, Sb, Qb, gamma + (size_t)L * D_HID, beta + (size_t)L * D_HID,
            w2f + (size_t)L * 8192, b2 + (size_t)L * D_IN,
            out, xbuf, rbuf, (L < 3) ? 1 : 0);
    }
}